// Round 6
// baseline (1627.008 us; speedup 1.0000x reference)
//
#include <hip/hip_runtime.h>

#define MIN_NORM 1e-15f
#define RCPF(x)  __builtin_amdgcn_rcpf(x)
#define SQRTF(x) __builtin_amdgcn_sqrtf(x)
#define RSQF(x)  __builtin_amdgcn_rsqf(x)

// butterfly sum within each 16-lane group via DPP row_ror (pure VALU)
__device__ __forceinline__ float rsum16(float v) {
    v += __int_as_float(__builtin_amdgcn_update_dpp(0, __float_as_int(v), 0x121, 0xF, 0xF, false)); // ror:1
    v += __int_as_float(__builtin_amdgcn_update_dpp(0, __float_as_int(v), 0x122, 0xF, 0xF, false)); // ror:2
    v += __int_as_float(__builtin_amdgcn_update_dpp(0, __float_as_int(v), 0x124, 0xF, 0xF, false)); // ror:4
    v += __int_as_float(__builtin_amdgcn_update_dpp(0, __float_as_int(v), 0x128, 0xF, 0xF, false)); // ror:8
    return v;
}

// tanh for x >= 0 via hardware exp
__device__ __forceinline__ float tanh_fast(float x) {
    float ex = __expf(fminf(2.f * x, 30.f));
    return (ex - 1.f) * RCPF(ex + 1.f);
}

// per-entity scalars: {scp, p2, nt, inv_nt}
__device__ __forceinline__ float4 prep_scalars(float n2) {
    float nh     = fmaxf(SQRTF(fmaxf(n2, 0.f)), MIN_NORM);
    float inv_nh = RCPF(nh);
    float th     = tanh_fast(nh);
    return make_float4(th * inv_nh, th * th, nh, inv_nh);
}

// ---------------- edge sort by head (count/scan/scatter) ----------------
__global__ __launch_bounds__(256) void k_count(const int* __restrict__ head,
                                               int* __restrict__ C, int E) {
    int i = blockIdx.x * 256 + (int)threadIdx.x;
    if (i < E) atomicAdd(&C[head[i]], 1);
}

__global__ __launch_bounds__(256) void k_scan1(const int* __restrict__ C,
                                               int* __restrict__ T,
                                               int* __restrict__ BS, int N) {
    __shared__ int lds[256];
    int i = blockIdx.x * 256 + (int)threadIdx.x;
    int v = (i < N) ? C[i] : 0;
    lds[threadIdx.x] = v;
    __syncthreads();
    for (int off = 1; off < 256; off <<= 1) {
        int add = (threadIdx.x >= (unsigned)off) ? lds[threadIdx.x - off] : 0;
        __syncthreads();
        lds[threadIdx.x] += add;
        __syncthreads();
    }
    if (i < N) T[i] = lds[threadIdx.x];
    if (threadIdx.x == 255) BS[blockIdx.x] = lds[255];
}

__global__ __launch_bounds__(1024) void k_scan2(int* __restrict__ BS, int nb) {
    __shared__ int lds[1024];
    int v = ((int)threadIdx.x < nb) ? BS[threadIdx.x] : 0;
    lds[threadIdx.x] = v;
    __syncthreads();
    for (int off = 1; off < 1024; off <<= 1) {
        int add = (threadIdx.x >= (unsigned)off) ? lds[threadIdx.x - off] : 0;
        __syncthreads();
        lds[threadIdx.x] += add;
        __syncthreads();
    }
    if ((int)threadIdx.x < nb) BS[threadIdx.x] = lds[threadIdx.x] - v;  // exclusive
}

__global__ __launch_bounds__(256) void k_scan3(const int* __restrict__ C,
                                               const int* __restrict__ T,
                                               const int* __restrict__ BS,
                                               int* __restrict__ P, int N) {
    int i = blockIdx.x * 256 + (int)threadIdx.x;
    if (i < N) P[i] = T[i] - C[i] + BS[blockIdx.x];
}

__global__ __launch_bounds__(256) void k_scatter(const int* __restrict__ head,
                                                 const int* __restrict__ tail,
                                                 const int* __restrict__ etype,
                                                 int* __restrict__ P,
                                                 int4* __restrict__ rec, int E) {
    int i = blockIdx.x * 256 + (int)threadIdx.x;
    if (i < E) {
        int h = head[i];
        int pos = atomicAdd(&P[h], 1);
        rec[pos] = make_int4(h, tail[i], etype[i] - 1, 0);
    }
}

// ---------------- tables ----------------
__global__ __launch_bounds__(256) void k_prep(const float4* __restrict__ src,
                                              float4* __restrict__ T, int N) {
    int gid = (blockIdx.x * 256 + (int)threadIdx.x) >> 4;
    int g   = (int)threadIdx.x & 15;
    if (gid >= N) return;
    float4 v = src[(size_t)gid * 16 + g];
    float n2 = rsum16(v.x * v.x + v.y * v.y + v.z * v.z + v.w * v.w);
    if (g == 0) T[gid] = prep_scalars(n2);
}

__global__ __launch_bounds__(256) void k_prep_rel(const float4* __restrict__ rel,
                                                  float4* __restrict__ RelC, int NR) {
    int gid = (blockIdx.x * 256 + (int)threadIdx.x) >> 4;
    int g   = (int)threadIdx.x & 15;
    if (gid >= NR) return;
    float4 v = rel[(size_t)gid * 16 + g];
    float n2 = rsum16(v.x * v.x + v.y * v.y + v.z * v.z + v.w * v.w);
    if (g == 0) {
        float nr = fmaxf(SQRTF(n2), MIN_NORM);
        RelC[gid] = make_float4(nr, RCPF(nr), n2, 0.f);
    }
}

// ---------------- edge kernel: 16 lanes/edge, head-sorted records ----------------
__global__ __launch_bounds__(256) void rgat_edge_kernel(
    const float*  __restrict__ e,      // [N,64]
    const float*  __restrict__ rel,    // [32,64]
    const float4* __restrict__ T,      // [N] {scp,p2,nt,inv_nt}
    const float4* __restrict__ RelC,   // [32] {nr,inv_nr,rr,0}
    const int4*   __restrict__ rec,    // [E] (head, tail, rtype, 0), head-sorted
    float*        __restrict__ sums,   // [N,64] pre-zeroed (= d_out)
    int E)
{
    int tid = blockIdx.x * 256 + (int)threadIdx.x;
    int eid = tid >> 4;
    int g   = (int)threadIdx.x & 15;
    if (eid >= E) return;

    int4 rc = rec[eid];
    int hi = rc.x, ti = rc.y, ri = rc.z;

    float4 Th = T[hi];      // .x=scp .y=p2
    float4 Tt = T[ti];      // .z=nt  .w=inv_nt
    float4 Rc = RelC[ri];   // .x=nr  .y=inv_nr .z=rr
    float scp = Th.x, p2 = Th.y;
    float nt = Tt.z, inv_nt = Tt.w;
    float nr = Rc.x, inv_nr = Rc.y, rr = Rc.z;

    const float* hrow = e   + (size_t)hi * 64 + g;
    const float* trow = e   + (size_t)ti * 64 + g;
    const float* rrow = rel + (size_t)ri * 64 + g;

    float h[4], t[4], r[4], trl[4];
#pragma unroll
    for (int k = 0; k < 4; ++k) {
        h[k] = hrow[k * 16];
        t[k] = trow[k * 16];
        r[k] = rrow[k * 16];
    }

    float pht = 0.f, phr = 0.f, ptr_ = 0.f;
#pragma unroll
    for (int k = 0; k < 4; ++k) {
        trl[k] = t[k] + r[k];
        pht += h[k] * t[k];
        phr += h[k] * r[k];
        ptr_ += t[k] * r[k];
    }
    float ht  = rsum16(pht);
    float hr  = rsum16(phr);
    float ttr = rsum16(ptr_);

    float tt   = nt * nt;
    float ntr2 = fmaf(2.f, ttr, tt + rr);        // |t+r|^2
    float bet  = fmaxf(1.f - p2, MIN_NORM);      // = lam_inv
    float ilam = RCPF(bet);                      // = lam/2

    float tht = tanh_fast(ilam * nt);
    float sct = tht * inv_nt;
    float y2t = tht * tht;
    float xyt = scp * sct * ht;

    float thr_ = tanh_fast(ilam * nr);
    float scr  = thr_ * inv_nr;
    float y2r  = thr_ * thr_;
    float xyr  = scp * scr * hr;

    // a = mobius_add(p, yt), b = mobius_add(p, yr)
    float alt  = fmaf(2.f, xyt, 1.f + y2t);
    float dent = fmaxf(fmaf(p2, y2t, fmaf(2.f, xyt, 1.f)), MIN_NORM);
    float alr  = fmaf(2.f, xyr, 1.f + y2r);
    float denr = fmaxf(fmaf(p2, y2r, fmaf(2.f, xyr, 1.f)), MIN_NORM);
    float iS   = RCPF(dent * denr);
    float idt  = iS * denr;
    float idr  = iS * dent;

    float a2 = (alt * alt * p2 + 2.f * alt * bet * xyt + bet * bet * y2t) * idt * idt;
    float pa = fmaf(bet, xyt, alt * p2) * idt;
    float b2 = (alr * alr * p2 + 2.f * alr * bet * xyr + bet * bet * y2r) * idr * idr;
    float pb = fmaf(bet, xyr, alr * p2) * idr;

    float ytyr = sct * scr * ttr;
    float ab = (alt * alr * p2 + alt * bet * xyr + bet * alr * xyt + bet * bet * ytyr) * idt * idr;

    // m = mobius_add(a, b)
    float am   = fmaf(2.f, ab, 1.f + b2);
    float bm   = 1.f - a2;
    float denm = fmaxf(fmaf(a2, b2, fmaf(2.f, ab, 1.f)), MIN_NORM);
    float idm  = RCPF(denm);
    float m2  = (am * am * a2 + 2.f * am * bm * ab + bm * bm * b2) * idm * idm;
    float pmv = fmaf(am, pa, bm * pb) * idm;

    // project via m2 compare (no sqrt)
    const float maxn  = 1.f - 4e-3f;
    const float maxn2 = maxn * maxn;
    float irm = RSQF(fmaxf(m2, 1e-30f));
    float sc  = (m2 > maxn2) ? (maxn * irm) : 1.f;
    m2  *= sc * sc;
    pmv *= sc;

    // logmap scalars
    float cs   = fmaf(-2.f, pmv, 1.f + m2);
    float dens = fmaxf(fmaf(p2, m2, fmaf(-2.f, pmv, 1.f)), MIN_NORM);
    float ids  = RCPF(dens);
    float s2  = fmaxf((cs * cs * p2 - 2.f * cs * bet * pmv + bet * bet * m2) * ids * ids, 1e-30f);
    float irs = RSQF(s2);
    float ns  = s2 * irs;                         // sqrt(s2)
    float xa  = fminf(ns, 1.f - 1e-7f);
    float ath = 0.5f * __logf((1.f + xa) * RCPF(1.f - xa));
    float lgs = bet * ath * irs;                  // lam_inv * artanh(ns)/ns

    float iric = RSQF(fmaxf(ntr2, 1e-24f));

    float bst = bet * sct, bsr = bet * scr, idms = idm * sc;
    float* dst = &sums[(size_t)hi * 64 + g];
#pragma unroll
    for (int k = 0; k < 4; ++k) {
        float p_l = scp * h[k];
        float a_l = fmaf(alt, p_l, bst * t[k]) * idt;
        float b_l = fmaf(alr, p_l, bsr * r[k]) * idr;
        float m_l = fmaf(am, a_l, bm * b_l) * idms;
        float s_l = (bet * m_l - cs * p_l) * ids;
        float res = fmaxf(fmaf(lgs, s_l, 1e-7f * (trl[k] * iric)), 0.f);
        atomicAdd(dst + k * 16, res);
    }
}

// hop-1 epilogue: e1n = normalize(sums) -> A; refresh T for hop 2
__global__ __launch_bounds__(256) void k_entity1(const float4* __restrict__ sums,
                                                 float4* __restrict__ A,
                                                 float4* __restrict__ T, int N) {
    int gid = (blockIdx.x * 256 + (int)threadIdx.x) >> 4;
    int g   = (int)threadIdx.x & 15;
    if (gid >= N) return;
    size_t idx = (size_t)gid * 16 + g;
    float4 s = sums[idx];
    float n2 = rsum16(s.x * s.x + s.y * s.y + s.z * s.z + s.w * s.w);
    float inv = RCPF(fmaxf(SQRTF(n2), 1e-12f));
    float4 v = make_float4(s.x * inv, s.y * inv, s.z * inv, s.w * inv);
    A[idx] = v;
    float n2v = rsum16(v.x * v.x + v.y * v.y + v.z * v.z + v.w * v.w);
    if (g == 0) T[gid] = prep_scalars(n2v);
}

// hop-2 epilogue (in place on d_out): out = 0.25*ent + 0.5*e1n + normalize(sums2)
__global__ __launch_bounds__(256) void k_entity2(float4* __restrict__ out,
                                                 const float4* __restrict__ ent,
                                                 const float4* __restrict__ A, int N) {
    int gid = (blockIdx.x * 256 + (int)threadIdx.x) >> 4;
    int g   = (int)threadIdx.x & 15;
    if (gid >= N) return;
    size_t idx = (size_t)gid * 16 + g;
    float4 s = out[idx];
    float n2 = rsum16(s.x * s.x + s.y * s.y + s.z * s.z + s.w * s.w);
    float inv = RCPF(fmaxf(SQRTF(n2), 1e-12f));
    float4 en = ent[idx];
    float4 a  = A[idx];
    float4 o;
    o.x = fmaf(0.25f, en.x, fmaf(0.5f, a.x, s.x * inv));
    o.y = fmaf(0.25f, en.y, fmaf(0.5f, a.y, s.y * inv));
    o.z = fmaf(0.25f, en.z, fmaf(0.5f, a.z, s.z * inv));
    o.w = fmaf(0.25f, en.w, fmaf(0.5f, a.w, s.w * inv));
    out[idx] = o;
}

extern "C" void kernel_launch(void* const* d_in, const int* in_sizes, int n_in,
                              void* d_out, int out_size, void* d_ws, size_t ws_size,
                              hipStream_t stream)
{
    const float* ent   = (const float*)d_in[0];   // [N,64]
    const float* rel   = (const float*)d_in[1];   // [32,64]
    const int*   eidx  = (const int*)d_in[2];     // [2,E]
    const int*   etype = (const int*)d_in[3];     // [E]

    int E = in_sizes[3];
    int N = in_sizes[0] / 64;
    int NR = in_sizes[1] / 64;
    const int* head = eidx;
    const int* tail = eidx + E;

    // ws: A[N*64 f32] | rec[E int4] | T[N float4] | RelC | P,C,Tsc int[N] | BS[1024]
    float*  A    = (float*)d_ws;                       // 51.2 MB
    int4*   rec  = (int4*)(A + (size_t)N * 64);        // 16 MB
    float4* T    = (float4*)(rec + E);                 // 3.2 MB
    float4* RelC = T + N;
    int*    P    = (int*)(RelC + NR);
    int*    C    = P + N;
    int*    Tsc  = C + N;
    int*    BS   = Tsc + N;                            // <=1024 ints

    int NB = (N + 255) / 256;       // 782 (<=1024)
    int EB = (E + 255) / 256;

    float* out = (float*)d_out;
    size_t embBytes = (size_t)N * 64 * sizeof(float);

    dim3 blk(256);
    int prepGrid = (N * 16 + 255) / 256;
    int relGrid  = (NR * 16 + 255) / 256;
    int edgeGrid = (E * 16 + 255) / 256;

    // sort edges by head (reused by both hops)
    hipMemsetAsync(C, 0, (size_t)N * sizeof(int), stream);
    k_count  <<<EB, blk, 0, stream>>>(head, C, E);
    k_scan1  <<<NB, blk, 0, stream>>>(C, Tsc, BS, N);
    k_scan2  <<<1, 1024, 0, stream>>>(BS, NB);
    k_scan3  <<<NB, blk, 0, stream>>>(C, Tsc, BS, P, N);
    k_scatter<<<EB, blk, 0, stream>>>(head, tail, etype, P, rec, E);

    // tables for hop 1
    k_prep    <<<prepGrid, blk, 0, stream>>>((const float4*)ent, T, N);
    k_prep_rel<<<relGrid,  blk, 0, stream>>>((const float4*)rel, RelC, NR);

    // hop 1: scatter into d_out, normalize -> A, refresh T
    hipMemsetAsync(out, 0, embBytes, stream);
    rgat_edge_kernel<<<edgeGrid, blk, 0, stream>>>(ent, rel, T, RelC, rec, out, E);
    k_entity1<<<prepGrid, blk, 0, stream>>>((const float4*)out, (float4*)A, T, N);

    // hop 2: scatter into d_out, fuse residual in place
    hipMemsetAsync(out, 0, embBytes, stream);
    rgat_edge_kernel<<<edgeGrid, blk, 0, stream>>>(A, rel, T, RelC, rec, out, E);
    k_entity2<<<prepGrid, blk, 0, stream>>>((float4*)out, (const float4*)ent, (const float4*)A, N);
}

// Round 7
// 441.340 us; speedup vs baseline: 3.6865x; 3.6865x over previous
//
#include <hip/hip_runtime.h>

#define MIN_NORM 1e-15f
#define RCPF(x)  __builtin_amdgcn_rcpf(x)
#define SQRTF(x) __builtin_amdgcn_sqrtf(x)
#define RSQF(x)  __builtin_amdgcn_rsqf(x)

// butterfly sum within each 16-lane group via DPP row_ror (pure VALU)
__device__ __forceinline__ float rsum16(float v) {
    v += __int_as_float(__builtin_amdgcn_update_dpp(0, __float_as_int(v), 0x121, 0xF, 0xF, false)); // ror:1
    v += __int_as_float(__builtin_amdgcn_update_dpp(0, __float_as_int(v), 0x122, 0xF, 0xF, false)); // ror:2
    v += __int_as_float(__builtin_amdgcn_update_dpp(0, __float_as_int(v), 0x124, 0xF, 0xF, false)); // ror:4
    v += __int_as_float(__builtin_amdgcn_update_dpp(0, __float_as_int(v), 0x128, 0xF, 0xF, false)); // ror:8
    return v;
}

// tanh for x >= 0 via hardware exp
__device__ __forceinline__ float tanh_fast(float x) {
    float ex = __expf(fminf(2.f * x, 30.f));
    return (ex - 1.f) * RCPF(ex + 1.f);
}

// per-entity scalars: {scp, p2, nt, inv_nt}
__device__ __forceinline__ float4 prep_scalars(float n2) {
    float nh     = fmaxf(SQRTF(fmaxf(n2, 0.f)), MIN_NORM);
    float inv_nh = RCPF(nh);
    float th     = tanh_fast(nh);
    return make_float4(th * inv_nh, th * th, nh, inv_nh);
}

// ---------------- edge sort by head (count/scan/scatter) ----------------
__global__ __launch_bounds__(256) void k_count(const int* __restrict__ head,
                                               int* __restrict__ C, int E) {
    int i = blockIdx.x * 256 + (int)threadIdx.x;
    if (i < E) atomicAdd(&C[head[i]], 1);
}

__global__ __launch_bounds__(256) void k_scan1(const int* __restrict__ C,
                                               int* __restrict__ T,
                                               int* __restrict__ BS, int N) {
    __shared__ int lds[256];
    int i = blockIdx.x * 256 + (int)threadIdx.x;
    int v = (i < N) ? C[i] : 0;
    lds[threadIdx.x] = v;
    __syncthreads();
    for (int off = 1; off < 256; off <<= 1) {
        int add = (threadIdx.x >= (unsigned)off) ? lds[threadIdx.x - off] : 0;
        __syncthreads();
        lds[threadIdx.x] += add;
        __syncthreads();
    }
    if (i < N) T[i] = lds[threadIdx.x];
    if (threadIdx.x == 255) BS[blockIdx.x] = lds[255];
}

__global__ __launch_bounds__(1024) void k_scan2(int* __restrict__ BS, int nb) {
    __shared__ int lds[1024];
    int v = ((int)threadIdx.x < nb) ? BS[threadIdx.x] : 0;
    lds[threadIdx.x] = v;
    __syncthreads();
    for (int off = 1; off < 1024; off <<= 1) {
        int add = (threadIdx.x >= (unsigned)off) ? lds[threadIdx.x - off] : 0;
        __syncthreads();
        lds[threadIdx.x] += add;
        __syncthreads();
    }
    if ((int)threadIdx.x < nb) BS[threadIdx.x] = lds[threadIdx.x] - v;  // exclusive
}

__global__ __launch_bounds__(256) void k_scan3(const int* __restrict__ C,
                                               const int* __restrict__ T,
                                               const int* __restrict__ BS,
                                               int* __restrict__ P, int N) {
    int i = blockIdx.x * 256 + (int)threadIdx.x;
    if (i < N) P[i] = T[i] - C[i] + BS[blockIdx.x];
}

__global__ __launch_bounds__(256) void k_scatter(const int* __restrict__ head,
                                                 const int* __restrict__ tail,
                                                 const int* __restrict__ etype,
                                                 int* __restrict__ P,
                                                 int4* __restrict__ rec, int E) {
    int i = blockIdx.x * 256 + (int)threadIdx.x;
    if (i < E) {
        int h = head[i];
        int pos = atomicAdd(&P[h], 1);
        rec[pos] = make_int4(h, tail[i], etype[i] - 1, 0);
    }
}

// ---------------- tables ----------------
__global__ __launch_bounds__(256) void k_prep(const float4* __restrict__ src,
                                              float4* __restrict__ T, int N) {
    int gid = (blockIdx.x * 256 + (int)threadIdx.x) >> 4;
    int g   = (int)threadIdx.x & 15;
    if (gid >= N) return;
    float4 v = src[(size_t)gid * 16 + g];
    float n2 = rsum16(v.x * v.x + v.y * v.y + v.z * v.z + v.w * v.w);
    if (g == 0) T[gid] = prep_scalars(n2);
}

__global__ __launch_bounds__(256) void k_prep_rel(const float4* __restrict__ rel,
                                                  float4* __restrict__ RelC, int NR) {
    int gid = (blockIdx.x * 256 + (int)threadIdx.x) >> 4;
    int g   = (int)threadIdx.x & 15;
    if (gid >= NR) return;
    float4 v = rel[(size_t)gid * 16 + g];
    float n2 = rsum16(v.x * v.x + v.y * v.y + v.z * v.z + v.w * v.w);
    if (g == 0) {
        float nr = fmaxf(SQRTF(n2), MIN_NORM);
        RelC[gid] = make_float4(nr, RCPF(nr), n2, 0.f);
    }
}

// ------- edge kernel: 16 lanes/edge, head-sorted, wave-segmented merge -------
__global__ __launch_bounds__(256) void rgat_edge_kernel(
    const float*  __restrict__ e,      // [N,64]
    const float*  __restrict__ rel,    // [32,64]
    const float4* __restrict__ T,      // [N] {scp,p2,nt,inv_nt}
    const float4* __restrict__ RelC,   // [32] {nr,inv_nr,rr,0}
    const int4*   __restrict__ rec,    // [E] (head, tail, rtype, 0), head-sorted
    float*        __restrict__ sums,   // [N,64] pre-zeroed (= d_out)
    int E)
{
    int tid = blockIdx.x * 256 + (int)threadIdx.x;
    int eid = tid >> 4;
    int g   = (int)threadIdx.x & 15;
    int s   = ((int)threadIdx.x >> 4) & 3;   // sub-edge slot within wave
    bool act = eid < E;
    int ec = act ? eid : (E - 1);

    int4 rc = rec[ec];
    int hi = rc.x, ti = rc.y, ri = rc.z;

    float4 Th = T[hi];      // .x=scp .y=p2
    float4 Tt = T[ti];      // .z=nt  .w=inv_nt
    float4 Rc = RelC[ri];   // .x=nr  .y=inv_nr .z=rr
    float scp = Th.x, p2 = Th.y;
    float nt = Tt.z, inv_nt = Tt.w;
    float nr = Rc.x, inv_nr = Rc.y, rr = Rc.z;

    const float* hrow = e   + (size_t)hi * 64 + g;
    const float* trow = e   + (size_t)ti * 64 + g;
    const float* rrow = rel + (size_t)ri * 64 + g;

    float h[4], t[4], r[4], trl[4];
#pragma unroll
    for (int k = 0; k < 4; ++k) {
        h[k] = hrow[k * 16];
        t[k] = trow[k * 16];
        r[k] = rrow[k * 16];
    }

    float pht = 0.f, phr = 0.f, ptr_ = 0.f;
#pragma unroll
    for (int k = 0; k < 4; ++k) {
        trl[k] = t[k] + r[k];
        pht += h[k] * t[k];
        phr += h[k] * r[k];
        ptr_ += t[k] * r[k];
    }
    float ht  = rsum16(pht);
    float hr  = rsum16(phr);
    float ttr = rsum16(ptr_);

    float tt   = nt * nt;
    float ntr2 = fmaf(2.f, ttr, tt + rr);        // |t+r|^2
    float bet  = fmaxf(1.f - p2, MIN_NORM);      // = lam_inv
    float ilam = RCPF(bet);                      // = lam/2

    float tht = tanh_fast(ilam * nt);
    float sct = tht * inv_nt;
    float y2t = tht * tht;
    float xyt = scp * sct * ht;

    float thr_ = tanh_fast(ilam * nr);
    float scr  = thr_ * inv_nr;
    float y2r  = thr_ * thr_;
    float xyr  = scp * scr * hr;

    // a = mobius_add(p, yt), b = mobius_add(p, yr)
    float alt  = fmaf(2.f, xyt, 1.f + y2t);
    float dent = fmaxf(fmaf(p2, y2t, fmaf(2.f, xyt, 1.f)), MIN_NORM);
    float alr  = fmaf(2.f, xyr, 1.f + y2r);
    float denr = fmaxf(fmaf(p2, y2r, fmaf(2.f, xyr, 1.f)), MIN_NORM);
    float iS   = RCPF(dent * denr);
    float idt  = iS * denr;
    float idr  = iS * dent;

    float a2 = (alt * alt * p2 + 2.f * alt * bet * xyt + bet * bet * y2t) * idt * idt;
    float pa = fmaf(bet, xyt, alt * p2) * idt;
    float b2 = (alr * alr * p2 + 2.f * alr * bet * xyr + bet * bet * y2r) * idr * idr;
    float pb = fmaf(bet, xyr, alr * p2) * idr;

    float ytyr = sct * scr * ttr;
    float ab = (alt * alr * p2 + alt * bet * xyr + bet * alr * xyt + bet * bet * ytyr) * idt * idr;

    // m = mobius_add(a, b)
    float am   = fmaf(2.f, ab, 1.f + b2);
    float bm   = 1.f - a2;
    float denm = fmaxf(fmaf(a2, b2, fmaf(2.f, ab, 1.f)), MIN_NORM);
    float idm  = RCPF(denm);
    float m2  = (am * am * a2 + 2.f * am * bm * ab + bm * bm * b2) * idm * idm;
    float pmv = fmaf(am, pa, bm * pb) * idm;

    // project via m2 compare (no sqrt)
    const float maxn  = 1.f - 4e-3f;
    const float maxn2 = maxn * maxn;
    float irm = RSQF(fmaxf(m2, 1e-30f));
    float sc  = (m2 > maxn2) ? (maxn * irm) : 1.f;
    m2  *= sc * sc;
    pmv *= sc;

    // logmap scalars
    float cs   = fmaf(-2.f, pmv, 1.f + m2);
    float dens = fmaxf(fmaf(p2, m2, fmaf(-2.f, pmv, 1.f)), MIN_NORM);
    float ids  = RCPF(dens);
    float s2  = fmaxf((cs * cs * p2 - 2.f * cs * bet * pmv + bet * bet * m2) * ids * ids, 1e-30f);
    float irs = RSQF(s2);
    float ns  = s2 * irs;                         // sqrt(s2)
    float xa  = fminf(ns, 1.f - 1e-7f);
    float ath = 0.5f * __logf((1.f + xa) * RCPF(1.f - xa));
    float lgs = bet * ath * irs;                  // lam_inv * artanh(ns)/ns

    float iric = RSQF(fmaxf(ntr2, 1e-24f));

    float amask = act ? 1.f : 0.f;
    float bst = bet * sct, bsr = bet * scr, idms = idm * sc;
    float res[4];
#pragma unroll
    for (int k = 0; k < 4; ++k) {
        float p_l = scp * h[k];
        float a_l = fmaf(alt, p_l, bst * t[k]) * idt;
        float b_l = fmaf(alr, p_l, bsr * r[k]) * idr;
        float m_l = fmaf(am, a_l, bm * b_l) * idms;
        float s_l = (bet * m_l - cs * p_l) * ids;
        res[k] = fmaxf(fmaf(lgs, s_l, 1e-7f * (trl[k] * iric)), 0.f) * amask;
    }

    // --- wave-level segmented suffix-merge across the 4 sorted sub-edges ---
    int hnext1 = __shfl_down(hi, 16, 64);
    int hnext2 = __shfl_down(hi, 32, 64);
    int hprev  = __shfl_up(hi, 16, 64);
    bool m1 = (s < 3) && (hnext1 == hi);
    bool m2k = (s < 2) && (hnext2 == hi);   // sorted => implies contiguity
    bool owner = (s == 0) || (hprev != hi);
#pragma unroll
    for (int k = 0; k < 4; ++k) {
        float v1 = __shfl_down(res[k], 16, 64);
        res[k] += m1 ? v1 : 0.f;
        float v2 = __shfl_down(res[k], 32, 64);
        res[k] += m2k ? v2 : 0.f;
    }

    if (owner) {
        float* dst = &sums[(size_t)hi * 64 + g];
#pragma unroll
        for (int k = 0; k < 4; ++k) atomicAdd(dst + k * 16, res[k]);
    }
}

// hop-1 epilogue: e1n = normalize(sums) -> A; zero out for hop 2; refresh T
__global__ __launch_bounds__(256) void k_entity1(float4* __restrict__ sums,
                                                 float4* __restrict__ A,
                                                 float4* __restrict__ T, int N) {
    int gid = (blockIdx.x * 256 + (int)threadIdx.x) >> 4;
    int g   = (int)threadIdx.x & 15;
    if (gid >= N) return;
    size_t idx = (size_t)gid * 16 + g;
    float4 s = sums[idx];
    sums[idx] = make_float4(0.f, 0.f, 0.f, 0.f);   // zero for hop 2
    float n2 = rsum16(s.x * s.x + s.y * s.y + s.z * s.z + s.w * s.w);
    float inv = RCPF(fmaxf(SQRTF(n2), 1e-12f));
    float4 v = make_float4(s.x * inv, s.y * inv, s.z * inv, s.w * inv);
    A[idx] = v;
    float n2v = rsum16(v.x * v.x + v.y * v.y + v.z * v.z + v.w * v.w);
    if (g == 0) T[gid] = prep_scalars(n2v);
}

// hop-2 epilogue (in place on d_out): out = 0.25*ent + 0.5*e1n + normalize(sums2)
__global__ __launch_bounds__(256) void k_entity2(float4* __restrict__ out,
                                                 const float4* __restrict__ ent,
                                                 const float4* __restrict__ A, int N) {
    int gid = (blockIdx.x * 256 + (int)threadIdx.x) >> 4;
    int g   = (int)threadIdx.x & 15;
    if (gid >= N) return;
    size_t idx = (size_t)gid * 16 + g;
    float4 s = out[idx];
    float n2 = rsum16(s.x * s.x + s.y * s.y + s.z * s.z + s.w * s.w);
    float inv = RCPF(fmaxf(SQRTF(n2), 1e-12f));
    float4 en = ent[idx];
    float4 a  = A[idx];
    float4 o;
    o.x = fmaf(0.25f, en.x, fmaf(0.5f, a.x, s.x * inv));
    o.y = fmaf(0.25f, en.y, fmaf(0.5f, a.y, s.y * inv));
    o.z = fmaf(0.25f, en.z, fmaf(0.5f, a.z, s.z * inv));
    o.w = fmaf(0.25f, en.w, fmaf(0.5f, a.w, s.w * inv));
    out[idx] = o;
}

extern "C" void kernel_launch(void* const* d_in, const int* in_sizes, int n_in,
                              void* d_out, int out_size, void* d_ws, size_t ws_size,
                              hipStream_t stream)
{
    const float* ent   = (const float*)d_in[0];   // [N,64]
    const float* rel   = (const float*)d_in[1];   // [32,64]
    const int*   eidx  = (const int*)d_in[2];     // [2,E]
    const int*   etype = (const int*)d_in[3];     // [E]

    int E = in_sizes[3];
    int N = in_sizes[0] / 64;
    int NR = in_sizes[1] / 64;
    const int* head = eidx;
    const int* tail = eidx + E;

    // ws: A[N*64 f32] | rec[E int4] | T[N float4] | RelC | P,C,Tsc int[N] | BS[1024]
    float*  A    = (float*)d_ws;                       // 51.2 MB
    int4*   rec  = (int4*)(A + (size_t)N * 64);        // 16 MB
    float4* T    = (float4*)(rec + E);                 // 3.2 MB
    float4* RelC = T + N;
    int*    P    = (int*)(RelC + NR);
    int*    C    = P + N;
    int*    Tsc  = C + N;
    int*    BS   = Tsc + N;                            // <=1024 ints

    int NB = (N + 255) / 256;       // 782 (<=1024)
    int EB = (E + 255) / 256;

    float* out = (float*)d_out;
    size_t embBytes = (size_t)N * 64 * sizeof(float);

    dim3 blk(256);
    int prepGrid = (N * 16 + 255) / 256;
    int relGrid  = (NR * 16 + 255) / 256;
    int edgeGrid = (E * 16 + 255) / 256;

    // sort edges by head (reused by both hops)
    hipMemsetAsync(C, 0, (size_t)N * sizeof(int), stream);
    k_count  <<<EB, blk, 0, stream>>>(head, C, E);
    k_scan1  <<<NB, blk, 0, stream>>>(C, Tsc, BS, N);
    k_scan2  <<<1, 1024, 0, stream>>>(BS, NB);
    k_scan3  <<<NB, blk, 0, stream>>>(C, Tsc, BS, P, N);
    k_scatter<<<EB, blk, 0, stream>>>(head, tail, etype, P, rec, E);

    // tables for hop 1
    k_prep    <<<prepGrid, blk, 0, stream>>>((const float4*)ent, T, N);
    k_prep_rel<<<relGrid,  blk, 0, stream>>>((const float4*)rel, RelC, NR);

    // hop 1: scatter into d_out, normalize -> A (also zeroes out), refresh T
    hipMemsetAsync(out, 0, embBytes, stream);
    rgat_edge_kernel<<<edgeGrid, blk, 0, stream>>>(ent, rel, T, RelC, rec, out, E);
    k_entity1<<<prepGrid, blk, 0, stream>>>((float4*)out, (float4*)A, T, N);

    // hop 2: scatter into d_out, fuse residual in place
    rgat_edge_kernel<<<edgeGrid, blk, 0, stream>>>(A, rel, T, RelC, rec, out, E);
    k_entity2<<<prepGrid, blk, 0, stream>>>((float4*)out, (const float4*)ent, (const float4*)A, N);
}